// Round 1
// baseline (245.345 us; speedup 1.0000x reference)
//
#include <hip/hip_runtime.h>

#define C_IN   672
#define C_OUT  128
#define HW     49
#define XELEMS (C_IN*HW)      // 32928
#define BK     96             // K-chunk (3 MFMA k-steps)
#define NCH    7              // 672/96
#define CHUNK  (BK*HW)        // 4704 floats per chunk
#define NLD    19             // ceil(4704/256) transform iterations
#define NDMA   19             // ceil(18816 B / 1024 B) global_load_lds issues per chunk
#define RAWSZ  4864           // 18*256 + 64*4 floats (clamped tail lands in [4704,4864))
#define RS     100            // hT row stride in halfs (200 B): write bank step 18 -> 4-way (~free, m136)
#define NROWS  64             // padded N (s) dimension

typedef short  short8  __attribute__((ext_vector_type(8)));
typedef short  short4v __attribute__((ext_vector_type(4)));
typedef float  f4      __attribute__((ext_vector_type(4)));

template<int N> struct IC { static constexpr int v = N; };

// counted vmcnt wait: N is a template param so the asm "n" constraint is a
// guaranteed ICE. "memory" clobber pins all memory ops (incl. the A-frag
// global loads and the DMA intrinsics) on their source side of the wait.
template<int N> __device__ __forceinline__ void waitvm() {
    asm volatile("s_waitcnt vmcnt(%0)" :: "n"(N) : "memory");
}
__device__ __forceinline__ void waitlgkm0() {
    asm volatile("s_waitcnt lgkmcnt(0)" ::: "memory");
}

__device__ __forceinline__ unsigned short f2bf(float f) {
    unsigned u = __float_as_uint(f);
    u += 0x7fffu + ((u >> 16) & 1u);
    return (unsigned short)(u >> 16);
}

__global__ __launch_bounds__(256) void prep_kernel(
        const float* __restrict__ gamma,
        const float* __restrict__ beta,
        const float* __restrict__ rmean,
        const float* __restrict__ rvar,
        const float* __restrict__ W,
        unsigned short* __restrict__ Wbf,
        float* __restrict__ scale,
        float* __restrict__ shift) {
    int i = blockIdx.x * 256 + threadIdx.x;
    if (i < C_IN) {
        float inv = rsqrtf(rvar[i] + 1e-5f);
        float sc  = gamma[i] * inv;
        scale[i] = sc;
        shift[i] = beta[i] - rmean[i] * sc;
    }
    if (i < C_OUT * C_IN) Wbf[i] = f2bf(W[i]);
}

// out_b(128x49) = W(128x672) @ relu(x_b*scale+shift)(672x49), one block per b.
// R6: full-slab prefetch. R5 was latency-phase-locked: 1-deep DMA pipeline,
// HBM round-trip (~900cy) hidden only by the ~200cy MFMA phase, and
// __syncthreads' implicit vmcnt(0) drained the queue every chunk -> 1.9 TB/s.
// Now: 7 raw landing buffers (154.4 KB LDS total, 1 block/CU) hold all of
// x[b]; ALL 35 DMA issues (133 KB) go out in the prologue, then chunks drain
// in-order with counted s_waitcnt vmcnt(5*rem) + raw s_barrier -- never
// vmcnt(0) until the last chunk (T3/T4, m218). A-fragments + scale/shift are
// loaded BEFORE the DMA queue: vmcnt completes in-order, so any vmem load
// issued after the DMAs would force a full drain on first use.
__global__ __launch_bounds__(256, 1) void gemm_kernel(
        const float* __restrict__ x,
        const unsigned short* __restrict__ Wbf,
        const float* __restrict__ scale,
        const float* __restrict__ shift,
        float* __restrict__ out) {
    __shared__ float s_scale[C_IN];
    __shared__ float s_shift[C_IN];
    __shared__ __align__(16) float raw[NCH * RAWSZ];   // 136192 B: 7 landing zones
    __shared__ unsigned short hT[NROWS * RS];          // 12800 B

    const int tid  = threadIdx.x;
    const int b    = blockIdx.x;
    const int wv   = tid >> 6;
    const int lane = tid & 63;
    const int quad = lane >> 4;
    const int l16  = lane & 15;

    const float* xb = x + (size_t)b * XELEMS;

    // zero hT once: pad rows 49..63 stay clean zeros for all chunks
    {
        unsigned long long* z = (unsigned long long*)hT;
        for (int i = tid; i < (NROWS * RS) / 4; i += 256) z[i] = 0ull;
    }
    // scale/shift staging FIRST in vmem issue order: the ds_write's implicit
    // vmcnt wait lands before any DMA is issued (one ~300cy stall per block).
    for (int i = tid; i < C_IN; i += 256) {
        s_scale[i] = scale[i];
        s_shift[i] = shift[i];
    }

    // Hoist ALL A-fragments to registers (42 x short8 = 168 VGPR/lane; W is
    // L2-resident bf16). Must precede DMA issuance (in-order vmcnt).
    short8 avv[NCH][3][2];
    #pragma unroll
    for (int ct = 0; ct < NCH; ++ct)
        #pragma unroll
        for (int ks = 0; ks < 3; ++ks)
            #pragma unroll
            for (int mt = 0; mt < 2; ++mt) {
                int row = wv * 32 + mt * 16 + l16;
                avv[ct][ks][mt] = *(const short8*)(Wbf + row * C_IN + ct * BK + ks * 32 + quad * 8);
            }

    // Fire-and-forget DMA of ALL 7 chunks, chunk-major per wave. Wave w
    // issues 5/5/5/4 per chunk (i = wv, wv+4, ...). LDS dest = uniform base +
    // lane*16 (m104); per-lane gptr clamped so the tail issue stays in-bounds
    // for b=1023. No vmem op may be issued after this until the epilogue.
    #pragma unroll
    for (int ct = 0; ct < NCH; ++ct) {
        const float* xsrc = xb + ct * CHUNK;
        for (int i = wv; i < NDMA; i += 4) {
            int fidx = i * 256 + lane * 4;
            if (fidx > CHUNK - 4) fidx = CHUNK - 4;
            __builtin_amdgcn_global_load_lds(
                (const __attribute__((address_space(1))) unsigned int*)(xsrc + fidx),
                (__attribute__((address_space(3))) unsigned int*)(raw + ct * RAWSZ + i * 256),
                16, 0, 0);
        }
    }
    waitlgkm0();   // hT zero-fill + scale ds_writes visible at first barrier

    f4 acc[2][4];
    #pragma unroll
    for (int mt = 0; mt < 2; ++mt)
        #pragma unroll
        for (int nt = 0; nt < 4; ++nt)
            acc[mt][nt] = (f4){0.f, 0.f, 0.f, 0.f};

    auto step = [&](auto itc) {
        constexpr int IT  = decltype(itc)::v;
        constexpr int REM = NCH - 1 - IT;
        // my chunk-IT DMAs complete when outstanding <= per-wave-count * REM.
        // Wave 3 issues 4/chunk, waves 0-2 issue 5/chunk (wave-uniform branch).
        if (wv == 3) waitvm<4 * REM>(); else waitvm<5 * REM>();
        __builtin_amdgcn_s_barrier();   // all waves: chunk-IT landed, hT reads of IT-1 done

        // transform: LDS raw -> BN+ReLU+bf16 -> hT
        const float* rawc = raw + IT * RAWSZ;
        #pragma unroll
        for (int i = 0; i < NLD; ++i) {
            int idx = i * 256 + tid;
            if (idx < CHUNK) {
                float rv = rawc[idx];
                int c = idx / HW;               // magic-div by 49
                int s = idx - c * HW;
                float v = fmaxf(rv * s_scale[IT * BK + c] + s_shift[IT * BK + c], 0.f);
                hT[s * RS + c] = f2bf(v);
            }
        }
        waitlgkm0();
        __builtin_amdgcn_s_barrier();   // all hT writes visible

        // 3 MFMA k-steps on hT
        #pragma unroll
        for (int ks = 0; ks < 3; ++ks) {
            const int kloc = ks * 32 + quad * 8;
            short8 bv[4];
            #pragma unroll
            for (int nt = 0; nt < 4; ++nt) {
                int srow = nt * 16 + l16;            // two ds_read_b64
                const unsigned short* p = hT + srow * RS + kloc;
                short4v lo = *(const short4v*)(p);
                short4v hi = *(const short4v*)(p + 4);
                bv[nt] = __builtin_shufflevector(lo, hi, 0, 1, 2, 3, 4, 5, 6, 7);
            }
            #pragma unroll
            for (int mt = 0; mt < 2; ++mt)
                #pragma unroll
                for (int nt = 0; nt < 4; ++nt)
                    acc[mt][nt] = __builtin_amdgcn_mfma_f32_16x16x32_bf16(
                        avv[IT][ks][mt], bv[nt], acc[mt][nt], 0, 0, 0);
        }
    };
    step(IC<0>{}); step(IC<1>{}); step(IC<2>{}); step(IC<3>{});
    step(IC<4>{}); step(IC<5>{}); step(IC<6>{});

    // epilogue: C/D layout col=lane&15, row=quad*4+reg (m89-verified); mask s>=49
    float* outb = out + (size_t)b * (C_OUT * HW);
    #pragma unroll
    for (int mt = 0; mt < 2; ++mt) {
        #pragma unroll
        for (int nt = 0; nt < 4; ++nt) {
            int scol = nt * 16 + l16;
            if (scol < HW) {
                #pragma unroll
                for (int i = 0; i < 4; ++i) {
                    int o = wv * 32 + mt * 16 + quad * 4 + i;
                    outb[o * HW + scol] = acc[mt][nt][i];
                }
            }
        }
    }
}

extern "C" void kernel_launch(void* const* d_in, const int* in_sizes, int n_in,
                              void* d_out, int out_size, void* d_ws, size_t ws_size,
                              hipStream_t stream) {
    const float* x     = (const float*)d_in[0];
    const float* gamma = (const float*)d_in[1];
    const float* beta  = (const float*)d_in[2];
    const float* rmean = (const float*)d_in[3];
    const float* rvar  = (const float*)d_in[4];
    const float* W     = (const float*)d_in[5];
    float* out = (float*)d_out;

    // ws layout: [bf16 W: 86016*2 B][scale: 672 f32][shift: 672 f32]  (~173 KB)
    unsigned short* Wbf = (unsigned short*)d_ws;
    float* scale = (float*)((char*)d_ws + (size_t)C_OUT * C_IN * 2);
    float* shift = scale + C_IN;

    prep_kernel<<<(C_OUT * C_IN + 255) / 256, 256, 0, stream>>>(
        gamma, beta, rmean, rvar, W, Wbf, scale, shift);
    gemm_kernel<<<1024, 256, 0, stream>>>(x, Wbf, scale, shift, out);
}

// Round 2
// 217.934 us; speedup vs baseline: 1.1258x; 1.1258x over previous
//
#include <hip/hip_runtime.h>

#define C_IN   672
#define C_OUT  128
#define HW     49
#define XELEMS (C_IN*HW)      // 32928
#define BK     96             // K-chunk (3 MFMA k-steps)
#define NCH    7              // 672/96
#define CHUNK  (BK*HW)        // 4704 floats per chunk
#define NLD2   10             // ceil(4704/512) transform iterations (512 thr)
#define NDMA   19             // ceil(18816 B / 1024 B) global_load_lds issues per chunk
#define RAWSZ  4864           // 18*256 + 64*4 floats (clamped tail lands in [4704,4864))
#define RS     100            // hT row stride in halfs (200 B): write bank step 18 -> 4-way (~free, m136)
#define NROWS  64             // padded N (s) dimension
#define NB     4              // batch elements per block
#define GRID   256            // 1024 / NB -> exactly 1 block per CU, no launch rounds

typedef short  short8  __attribute__((ext_vector_type(8)));
typedef short  short4v __attribute__((ext_vector_type(4)));
typedef float  f4      __attribute__((ext_vector_type(4)));

template<int N> struct IC { static constexpr int v = N; };

// counted vmcnt wait: N is a template param so the asm "n" constraint is a
// guaranteed ICE. "memory" clobber pins all memory ops on their side.
template<int N> __device__ __forceinline__ void waitvm() {
    asm volatile("s_waitcnt vmcnt(%0)" :: "n"(N) : "memory");
}
__device__ __forceinline__ void waitlgkm0() {
    asm volatile("s_waitcnt lgkmcnt(0)" ::: "memory");
}

__device__ __forceinline__ unsigned short f2bf(float f) {
    unsigned u = __float_as_uint(f);
    u += 0x7fffu + ((u >> 16) & 1u);
    return (unsigned short)(u >> 16);
}

__global__ __launch_bounds__(256) void prep_kernel(
        const float* __restrict__ gamma,
        const float* __restrict__ beta,
        const float* __restrict__ rmean,
        const float* __restrict__ rvar,
        const float* __restrict__ W,
        unsigned short* __restrict__ Wbf,
        float* __restrict__ scale,
        float* __restrict__ shift) {
    int i = blockIdx.x * 256 + threadIdx.x;
    if (i < C_IN) {
        float inv = rsqrtf(rvar[i] + 1e-5f);
        float sc  = gamma[i] * inv;
        scale[i] = sc;
        shift[i] = beta[i] - rmean[i] * sc;
    }
    if (i < C_OUT * C_IN) Wbf[i] = f2bf(W[i]);
}

// out_b(128x49) = W(128x672) @ relu(x_b*scale+shift)(672x49).
// R7: ring pipeline. R6 failed because avv (42 short8 = 168 VGPR @ 4 waves)
// didn't stay register-resident (VGPR_Count=144): the compiler sank the Wbf
// loads into the loop, after the DMA queue in vmem order, so each use forced
// a near-full vmcnt drain -> 752 GB/s.
// Fixes: (a) 512 threads / 8 waves -> avv is 21 short8 = 84 VGPR; (b) every
// fragment pinned with asm "+v" so it CANNOT be re-loaded; (c) each block
// processes NB=4 consecutive b's over a 7-buffer LDS ring: after chunk IT's
// transform frees raw[IT], the DMA for chunk IT of b+1 is issued into it.
// The DMA stream never drains (steady-state wait = vmcnt(6*cnt_w); vmcnt(0)
// only at the very last chunk of the 4th b). W-frags loaded once per block.
__global__ __launch_bounds__(512, 2) void gemm_kernel(
        const float* __restrict__ x,
        const unsigned short* __restrict__ Wbf,
        const float* __restrict__ scale,
        const float* __restrict__ shift,
        float* __restrict__ out) {
    __shared__ float s_scale[C_IN];
    __shared__ float s_shift[C_IN];
    __shared__ __align__(16) float raw[NCH * RAWSZ];   // 136192 B: 7-deep ring
    __shared__ unsigned short hT[NROWS * RS];          // 12800 B

    const int tid  = threadIdx.x;
    const int wv   = tid >> 6;          // 0..7
    const int lane = tid & 63;
    const int quad = lane >> 4;
    const int l16  = lane & 15;
    const int b0   = blockIdx.x * NB;

    // zero hT once: pad rows 49..63 stay clean zeros for all chunks
    {
        unsigned long long* z = (unsigned long long*)hT;
        for (int i = tid; i < (NROWS * RS) / 4; i += 512) z[i] = 0ull;
    }
    // scale/shift staging FIRST in vmem issue order (before any DMA)
    for (int i = tid; i < C_IN; i += 512) {
        s_scale[i] = scale[i];
        s_shift[i] = shift[i];
    }

    // Hoist ALL A-fragments: each wave owns 16 out-rows -> 21 short8 = 84 VGPR.
    // Loaded once per block (covers all NB b's). Must precede DMA issuance
    // (in-order vmcnt), and must STAY in registers: pin with asm "+v" so the
    // compiler cannot sink/re-materialize the loads past the DMA queue (R6 bug).
    short8 avv[NCH][3];
    #pragma unroll
    for (int ct = 0; ct < NCH; ++ct)
        #pragma unroll
        for (int ks = 0; ks < 3; ++ks) {
            int row = wv * 16 + l16;
            avv[ct][ks] = *(const short8*)(Wbf + row * C_IN + ct * BK + ks * 32 + quad * 8);
        }
    #pragma unroll
    for (int ct = 0; ct < NCH; ++ct)
        #pragma unroll
        for (int ks = 0; ks < 3; ++ks)
            asm volatile("" : "+v"(avv[ct][ks]));
    asm volatile("" ::: "memory");      // fence: nothing crosses into DMA region

    // DMA one chunk into ring slot IT. Per-chunk per-wave issue count:
    // wave 0..2 -> 3, wave 3..7 -> 2  (i = wv, wv+8, wv+16 < 19).
    auto dma_chunk = [&](const float* xsrc, int slot) {
        for (int i = wv; i < NDMA; i += 8) {
            int fidx = i * 256 + lane * 4;
            if (fidx > CHUNK - 4) fidx = CHUNK - 4;   // tail clamp, stays in-bounds
            __builtin_amdgcn_global_load_lds(
                (const __attribute__((address_space(1))) unsigned int*)(xsrc + fidx),
                (__attribute__((address_space(3))) unsigned int*)(raw + slot * RAWSZ + i * 256),
                16, 0, 0);
        }
    };

    // prologue: fire all 7 chunks of b0 (<= 21 outstanding per wave, < 63 cap)
    {
        const float* xb = x + (size_t)b0 * XELEMS;
        #pragma unroll
        for (int ct = 0; ct < NCH; ++ct) dma_chunk(xb + ct * CHUNK, ct);
    }
    waitlgkm0();   // own hT-zero + scale ds_writes done before first barrier

    f4 acc[4];
    #pragma unroll
    for (int nt = 0; nt < 4; ++nt) acc[nt] = (f4){0.f, 0.f, 0.f, 0.f};

    // One pipeline step: wait chunk (this b, IT) -> transform -> refill slot
    // with chunk IT of the NEXT b (if ISS) -> 12 MFMAs.
    // Wait math (per wave, in-order vmcnt): before the wait, groups g..g+REM
    // are outstanding; vmcnt(REM*cnt_w) drains exactly group g. Epilogue
    // stores between b's add <=16 newest ops -> wait over-drains a few ops of
    // group g+1 (harmless, they are 6 steps old).
    auto step = [&](auto itc, auto remc, auto issc, const float* xnext) {
        constexpr int  IT  = decltype(itc)::v;
        constexpr int  REM = decltype(remc)::v;
        constexpr bool ISS = decltype(issc)::v != 0;

        if (wv < 3) waitvm<REM * 3>(); else waitvm<REM * 2>();
        __builtin_amdgcn_s_barrier();   // chunk IT landed for all waves; hT reads of prev step done

        // transform: LDS raw -> BN+ReLU+bf16 -> hT
        const float* rawc = raw + IT * RAWSZ;
        #pragma unroll
        for (int i = 0; i < NLD2; ++i) {
            int idx = i * 512 + tid;
            if (idx < CHUNK) {
                float rv = rawc[idx];
                int c = idx / HW;               // magic-div by 49
                int s = idx - c * HW;
                float v = fmaxf(rv * s_scale[IT * BK + c] + s_shift[IT * BK + c], 0.f);
                hT[s * RS + c] = f2bf(v);
            }
        }
        waitlgkm0();
        __builtin_amdgcn_s_barrier();   // hT ready; all raw[IT] reads complete

        // slot IT is free: fire-and-forget refill with next b's chunk IT
        if (ISS) dma_chunk(xnext + IT * CHUNK, IT);

        // 3 MFMA k-steps on hT
        #pragma unroll
        for (int ks = 0; ks < 3; ++ks) {
            const int kloc = ks * 32 + quad * 8;
            short8 bv[4];
            #pragma unroll
            for (int nt = 0; nt < 4; ++nt) {
                int srow = nt * 16 + l16;            // two ds_read_b64
                const unsigned short* p = hT + srow * RS + kloc;
                short4v lo = *(const short4v*)(p);
                short4v hi = *(const short4v*)(p + 4);
                bv[nt] = __builtin_shufflevector(lo, hi, 0, 1, 2, 3, 4, 5, 6, 7);
            }
            #pragma unroll
            for (int nt = 0; nt < 4; ++nt)
                acc[nt] = __builtin_amdgcn_mfma_f32_16x16x32_bf16(
                    avv[IT][ks], bv[nt], acc[nt], 0, 0, 0);
        }
    };

    // epilogue for one b: C/D layout col=lane&15, row=quad*4+reg (m89); mask s>=49
    auto epilogue = [&](int b) {
        float* outb = out + (size_t)b * (C_OUT * HW);
        #pragma unroll
        for (int nt = 0; nt < 4; ++nt) {
            int scol = nt * 16 + l16;
            if (scol < HW) {
                #pragma unroll
                for (int i = 0; i < 4; ++i) {
                    int o = wv * 16 + quad * 4 + i;
                    outb[o * HW + scol] = acc[nt][i];
                }
            }
        }
        #pragma unroll
        for (int nt = 0; nt < 4; ++nt) acc[nt] = (f4){0.f, 0.f, 0.f, 0.f};
    };

    // b's 0..NB-2: steady state, REM=6, refill ring with next b's chunks
    #pragma unroll 1
    for (int bi = 0; bi < NB - 1; ++bi) {
        const float* xnext = x + (size_t)(b0 + bi + 1) * XELEMS;
        step(IC<0>{}, IC<6>{}, IC<1>{}, xnext);
        step(IC<1>{}, IC<6>{}, IC<1>{}, xnext);
        step(IC<2>{}, IC<6>{}, IC<1>{}, xnext);
        step(IC<3>{}, IC<6>{}, IC<1>{}, xnext);
        step(IC<4>{}, IC<6>{}, IC<1>{}, xnext);
        step(IC<5>{}, IC<6>{}, IC<1>{}, xnext);
        step(IC<6>{}, IC<6>{}, IC<1>{}, xnext);
        epilogue(b0 + bi);
    }
    // last b: stream drains, REM = 6-IT, no refill
    step(IC<0>{}, IC<6>{}, IC<0>{}, nullptr);
    step(IC<1>{}, IC<5>{}, IC<0>{}, nullptr);
    step(IC<2>{}, IC<4>{}, IC<0>{}, nullptr);
    step(IC<3>{}, IC<3>{}, IC<0>{}, nullptr);
    step(IC<4>{}, IC<2>{}, IC<0>{}, nullptr);
    step(IC<5>{}, IC<1>{}, IC<0>{}, nullptr);
    step(IC<6>{}, IC<0>{}, IC<0>{}, nullptr);
    epilogue(b0 + NB - 1);
}

extern "C" void kernel_launch(void* const* d_in, const int* in_sizes, int n_in,
                              void* d_out, int out_size, void* d_ws, size_t ws_size,
                              hipStream_t stream) {
    const float* x     = (const float*)d_in[0];
    const float* gamma = (const float*)d_in[1];
    const float* beta  = (const float*)d_in[2];
    const float* rmean = (const float*)d_in[3];
    const float* rvar  = (const float*)d_in[4];
    const float* W     = (const float*)d_in[5];
    float* out = (float*)d_out;

    // ws layout: [bf16 W: 86016*2 B][scale: 672 f32][shift: 672 f32]  (~173 KB)
    unsigned short* Wbf = (unsigned short*)d_ws;
    float* scale = (float*)((char*)d_ws + (size_t)C_OUT * C_IN * 2);
    float* shift = scale + C_IN;

    prep_kernel<<<(C_OUT * C_IN + 255) / 256, 256, 0, stream>>>(
        gamma, beta, rmean, rvar, W, Wbf, scale, shift);
    gemm_kernel<<<GRID, 512, 0, stream>>>(x, Wbf, scale, shift, out);
}

// Round 3
// 211.123 us; speedup vs baseline: 1.1621x; 1.0323x over previous
//
#include <hip/hip_runtime.h>

#define C_IN   672
#define C_OUT  128
#define HW     49
#define XELEMS (C_IN*HW)      // 32928
#define BK     96             // K-chunk (3 MFMA k-steps)
#define NCH    7              // 672/96
#define CHUNK  (BK*HW)        // 4704 floats per chunk
#define RS     100            // hT row stride in halfs (200 B): MFMA-read banks uniform, write ~4-way (~free)
#define NROWS  64             // padded N (s) dimension
#define SSPAD  680            // s_ss entries: 672 + pad for speculative c0+1 read

typedef short  short8  __attribute__((ext_vector_type(8)));
typedef short  short4v __attribute__((ext_vector_type(4)));
typedef float  f4      __attribute__((ext_vector_type(4)));
typedef float  f2      __attribute__((ext_vector_type(2)));

template<int N> struct IC { static constexpr int v = N; };

__device__ __forceinline__ void waitlgkm0() {
    asm volatile("s_waitcnt lgkmcnt(0)" ::: "memory");
}

__device__ __forceinline__ unsigned short f2bf(float f) {
    unsigned u = __float_as_uint(f);
    u += 0x7fffu + ((u >> 16) & 1u);
    return (unsigned short)(u >> 16);
}

__global__ __launch_bounds__(256) void prep_kernel(
        const float* __restrict__ gamma,
        const float* __restrict__ beta,
        const float* __restrict__ rmean,
        const float* __restrict__ rvar,
        const float* __restrict__ W,
        unsigned short* __restrict__ Wbf,
        float* __restrict__ scale,
        float* __restrict__ shift) {
    int i = blockIdx.x * 256 + threadIdx.x;
    if (i < C_IN) {
        float inv = rsqrtf(rvar[i] + 1e-5f);
        float sc  = gamma[i] * inv;
        scale[i] = sc;
        shift[i] = beta[i] - rmean[i] * sc;
    }
    if (i < C_OUT * C_IN) Wbf[i] = f2bf(W[i]);
}

// out_b(128x49) = W(128x672) @ relu(x_b*scale+shift)(672x49), one block per b.
// R8: reg-staged fused transform. R5 (1-deep DMA, 4 blk/CU) and R7 (6-deep
// ring, counted vmcnt, 1 blk/CU) both plateaued at the SAME time -> the
// shared global_load_lds -> raw[] -> LDS-read -> LDS-write path is the
// suspect, not the schedule. Now: x is loaded with plain coalesced float4
// (the m13 6.3 TB/s path) into registers, BN+ReLU+bf16 applied IN REGISTER,
// and only the 9.2 KB bf16 hT tile is ds_written (double-buffered). raw[]
// and all global_load_lds are gone (LDS 154 KB -> 31 KB, 2 blocks/CU).
// Barriers are raw s_barrier + lgkmcnt(0) only: in-flight x/W loads are
// never drained (use-based vmcnt at the consuming phase, compiler-inserted).
// Pipeline: loads for chunk kc+2 and W-frags for kc+1 issue during step kc.
__global__ __launch_bounds__(512, 4) void gemm_kernel(
        const float* __restrict__ x,
        const unsigned short* __restrict__ Wbf,
        const float* __restrict__ scale,
        const float* __restrict__ shift,
        float* __restrict__ out) {
    __shared__ f2 s_ss[SSPAD];                       // (scale,shift) interleaved
    __shared__ unsigned short hT[2][NROWS * RS];     // 2 x 12.8 KB double buffer

    const int tid  = threadIdx.x;
    const int wv   = tid >> 6;          // 0..7, owns out rows wv*16..+15
    const int lane = tid & 63;
    const int quad = lane >> 4;
    const int l16  = lane & 15;
    const float* xb = x + (size_t)blockIdx.x * XELEMS;

    // zero both hT buffers once: pad rows 49..63 stay clean zeros
    for (int i = tid; i < (2 * NROWS * RS) / 4; i += 512)
        ((unsigned long long*)hT)[i] = 0ull;
    // stage interleaved (scale,shift); zero the speculative-read pad
    for (int i = tid; i < C_IN; i += 512)
        s_ss[i] = (f2){scale[i], shift[i]};
    if (tid < SSPAD - C_IN) s_ss[C_IN + tid] = (f2){0.f, 0.f};

    // x chunk staging: 3 float4/thread (threads >=152 on r=2 clamp+discard).
    // Per wave per r: 1 KB contiguous -> fully coalesced.
    f4 xrA[3], xrB[3];
    auto issue_x = [&](int kc, f4* xr) {
        const float* src = xb + kc * CHUNK;
        #pragma unroll
        for (int r = 0; r < 3; ++r) {
            int base = r * 2048 + tid * 4;
            if (base > CHUNK - 4) base = CHUNK - 4;
            xr[r] = *(const f4*)(src + base);
        }
    };

    short8 av[3];                       // current chunk's A-frags (L2-hot W)
    auto issue_av = [&](int kc) {
        int row = wv * 16 + l16;
        #pragma unroll
        for (int ks = 0; ks < 3; ++ks)
            av[ks] = *(const short8*)(Wbf + row * C_IN + kc * BK + ks * 32 + quad * 8);
    };

    // BN+ReLU+bf16 in register, scatter b16 into transposed hT[buf].
    // c/s tracked incrementally (one magic-div per float4, +1 carry per elem).
    auto transform = [&](int kc, f4* xr, int buf) {
        unsigned short* h = &hT[buf][0];
        #pragma unroll
        for (int r = 0; r < 3; ++r) {
            int vb = r * 2048 + tid * 4;
            int cb = vb > CHUNK - 4 ? CHUNK - 4 : vb;   // matches issue_x clamp
            int c0 = cb / HW;                            // magic-div by 49
            int s0 = cb - c0 * HW;
            f2 p0 = s_ss[kc * BK + c0];
            f2 p1 = s_ss[kc * BK + c0 + 1];              // pad covers c0=95 edge
            #pragma unroll
            for (int jj = 0; jj < 4; ++jj) {
                int s = s0 + jj, c = c0;
                f2 pp = p0;
                if (s >= HW) { s -= HW; c = c0 + 1; pp = p1; }
                float v = fmaxf(xr[r][jj] * pp.x + pp.y, 0.f);
                if (r < 2 || vb + jj < CHUNK)            // r<2 folds to true
                    h[s * RS + c] = f2bf(v);
            }
        }
    };

    f4 acc[4];
    #pragma unroll
    for (int nt = 0; nt < 4; ++nt) acc[nt] = (f4){0.f, 0.f, 0.f, 0.f};

    auto mfma_phase = [&](int buf) {
        const unsigned short* h = &hT[buf][0];
        #pragma unroll
        for (int ks = 0; ks < 3; ++ks) {
            const int kloc = ks * 32 + quad * 8;
            short8 bv[4];
            #pragma unroll
            for (int nt = 0; nt < 4; ++nt) {
                int srow = nt * 16 + l16;                // bank-uniform ds_read_b64 pair
                const unsigned short* p = h + srow * RS + kloc;
                short4v lo = *(const short4v*)(p);
                short4v hi = *(const short4v*)(p + 4);
                bv[nt] = __builtin_shufflevector(lo, hi, 0, 1, 2, 3, 4, 5, 6, 7);
            }
            #pragma unroll
            for (int nt = 0; nt < 4; ++nt)
                acc[nt] = __builtin_amdgcn_mfma_f32_16x16x32_bf16(
                    av[ks], bv[nt], acc[nt], 0, 0, 0);
        }
    };

    // prologue
    issue_x(0, xrA);
    waitlgkm0();
    __builtin_amdgcn_s_barrier();       // s_ss + hT zeros visible (x(0) stays in flight)
    issue_av(0);                        // issued before x(1): in-order retire keeps waits decoupled
    transform(0, xrA, 0);               // waits x(0) on use
    issue_x(1, xrB);
    waitlgkm0();
    __builtin_amdgcn_s_barrier();       // hT[0] ready

    // steady state: MFMA(kc) from hT[kc&1] overlaps transform(kc+1) -> hT[~],
    // loads for kc+2 in flight across the barrier. One barrier per step:
    // passing barrier(kc) proves every wave finished MFMA(kc-1), so the
    // write of hT[kc&1] at step kc+1 is WAR-safe.
    auto step = [&](auto kcc) {
        constexpr int KC  = decltype(kcc)::v;
        constexpr int BUF = KC & 1;
        mfma_phase(BUF);
        if constexpr (KC < NCH - 1) {
            issue_av(KC + 1);                               // av dead after mfma_phase
            transform(KC + 1, (KC & 1) ? xrA : xrB, BUF ^ 1);
            if constexpr (KC < NCH - 2)
                issue_x(KC + 2, (KC & 1) ? xrB : xrA);      // set freed by transform(KC) last step
        }
        waitlgkm0();
        __builtin_amdgcn_s_barrier();
    };
    step(IC<0>{}); step(IC<1>{}); step(IC<2>{}); step(IC<3>{});
    step(IC<4>{}); step(IC<5>{}); step(IC<6>{});

    // epilogue: C/D layout col=lane&15, row=quad*4+reg (m89-verified); mask s>=49
    float* outb = out + (size_t)blockIdx.x * (C_OUT * HW);
    #pragma unroll
    for (int nt = 0; nt < 4; ++nt) {
        int scol = nt * 16 + l16;
        if (scol < HW) {
            #pragma unroll
            for (int i = 0; i < 4; ++i) {
                int o = wv * 16 + quad * 4 + i;
                outb[o * HW + scol] = acc[nt][i];
            }
        }
    }
}

extern "C" void kernel_launch(void* const* d_in, const int* in_sizes, int n_in,
                              void* d_out, int out_size, void* d_ws, size_t ws_size,
                              hipStream_t stream) {
    const float* x     = (const float*)d_in[0];
    const float* gamma = (const float*)d_in[1];
    const float* beta  = (const float*)d_in[2];
    const float* rmean = (const float*)d_in[3];
    const float* rvar  = (const float*)d_in[4];
    const float* W     = (const float*)d_in[5];
    float* out = (float*)d_out;

    // ws layout: [bf16 W: 86016*2 B][scale: 672 f32][shift: 672 f32]  (~173 KB)
    unsigned short* Wbf = (unsigned short*)d_ws;
    float* scale = (float*)((char*)d_ws + (size_t)C_OUT * C_IN * 2);
    float* shift = scale + C_IN;

    prep_kernel<<<(C_OUT * C_IN + 255) / 256, 256, 0, stream>>>(
        gamma, beta, rmean, rvar, W, Wbf, scale, shift);
    gemm_kernel<<<1024, 512, 0, stream>>>(x, Wbf, scale, shift, out);
}